// Round 28
// baseline (83.982 us; speedup 1.0000x reference)
//
#include <hip/hip_runtime.h>
#include <hip/hip_bf16.h>

// HPBC step — R=4 adjacent outputs + MOD-4-split gh (conflict-free FIR reads
// at 4tid stride) + sliding e-windows (2 e-reads/M) + ±m shared G/H +
// template FIR + static double buffers + pk-FMA + 4-plane split sE.
// Geometry (solved): dict inputs, true complex assembly; output chunks
// [E' | Eo], element storage (IMAG, REAL) per (b, i', pol); nout=65436, lpad=50.

namespace {

constexpr int NSEQ    = 65536;
constexpr int BATCH   = 8;
constexpr int KTAPS   = 449;
constexpr int NM      = 25;
constexpr int THREADS = 256;
constexpr int TILE    = 1024;                    // 4 outputs/thread, adjacent
constexpr int WIN     = TILE + 4 * NM;           // 1124
constexpr int WINQ    = WIN / 4;                 // 281
constexpr int GHW     = TILE + 2 * NM + 1;       // 1075
constexpr int GHQ     = (GHW + 3) / 4;           // 269 entries per class

typedef float v2f __attribute__((ext_vector_type(2)));

__device__ inline v2f pkfma(float s, v2f v, v2f acc) {
  return __builtin_elementwise_fma((v2f){s, s}, v, acc);
}

__device__ inline void mac(v2f& U13, v2f& U42, v2f& V13, v2f& V42,
                           const float4 c, const float4 g) {
  const v2f glo = (v2f){g.x, g.y}, ghi = (v2f){g.z, g.w};
  U13 = pkfma(c.x, glo, U13); U42 = pkfma(c.y, glo, U42);
  V13 = pkfma(c.z, ghi, V13); V42 = pkfma(c.w, ghi, V42);
}

__device__ inline unsigned short f2bf(float f) {
  __hip_bfloat16 h = __float2bfloat16(f);
  union { __hip_bfloat16 hh; unsigned short u; } cv;
  cv.hh = h;
  return cv.u;
}

// cw[row*K+k] = (c1r,c1i,c2r,c2i); cw[4K + row*K+k] = (c2r,c2i,c1r,c1i)
__global__ void prep_c_kernel(const float* __restrict__ c1r, const float* __restrict__ c1i,
                              const float* __restrict__ c2r, const float* __restrict__ c2i,
                              float4* __restrict__ cw) {
  int idx = blockIdx.x * blockDim.x + threadIdx.x;
  if (idx < 4 * KTAPS) {
    cw[idx]             = make_float4(c1r[idx], c1i[idx], c2r[idx], c2i[idx]);
    cw[4 * KTAPS + idx] = make_float4(c2r[idx], c2i[idx], c1r[idx], c1i[idx]);
  }
}

__device__ inline float4 gh_entry(const float4 e, const float4 f,
                                  const float4 fm, const float4 em) {
  v2f G = (v2f){fm.w * e.w, fm.w * (-e.z)};
  G = pkfma(fm.x, (v2f){e.x, e.y}, G);
  G = pkfma(fm.y, (v2f){e.y, -e.x}, G);
  G = pkfma(fm.z, (v2f){e.z, e.w}, G);
  v2f H = (v2f){em.w * f.w, em.w * (-f.z)};
  H = pkfma(em.x, (v2f){f.x, f.y}, H);
  H = pkfma(em.y, (v2f){f.y, -f.x}, H);
  H = pkfma(em.z, (v2f){f.z, f.w}, H);
  return make_float4(G.x, G.y, H.x, H.y);
}

// 4-output FIR walk over the mod-4-split gh (flattened: class c at c*GHQ).
// Step s (=4a+q) reads gh[Bq - a] where Bq = ((X-q)&3)*GHQ + tid + ((X-q)>>2);
// feeds output r at tap t = s-3+r (guards compile-time).
template<int NMAX>
__device__ inline void fir4(const float4* __restrict__ gh,
                            int B0, int B1, int B2, int B3,
                            const float4* __restrict__ cc,
                            v2f* __restrict__ acc /* [16] */)
{
  constexpr int T = 2 * NMAX + 1;
  float4 cw0, cw1, cw2, cw3;
#pragma unroll
  for (int s = 0; s <= T + 2; ++s) {
    const int q = s & 3, a = s >> 2;
    const int base = (q == 0) ? B0 : (q == 1) ? B1 : (q == 2) ? B2 : B3;
    const float4 g = gh[base - a];
    if (s < T) cw0 = cc[s];
    if (s <= T - 1)           mac(acc[12], acc[13], acc[14], acc[15], cw0, g);  // r=3
    if (s >= 1 && s <= T)     mac(acc[ 8], acc[ 9], acc[10], acc[11], cw1, g);  // r=2
    if (s >= 2 && s <= T + 1) mac(acc[ 4], acc[ 5], acc[ 6], acc[ 7], cw2, g);  // r=1
    if (s >= 3)               mac(acc[ 0], acc[ 1], acc[ 2], acc[ 3], cw3, g);  // r=0
    cw3 = cw2; cw2 = cw1; cw1 = cw0;
  }
}

#define FIR_SWITCH(NMX, GH_, B0_, B1_, B2_, B3_, CC, ACC) \
  switch (NMX) { \
    case 25: fir4<25>(GH_, B0_, B1_, B2_, B3_, CC, ACC); break; \
    case 12: fir4<12>(GH_, B0_, B1_, B2_, B3_, CC, ACC); break; \
    case  8: fir4< 8>(GH_, B0_, B1_, B2_, B3_, CC, ACC); break; \
    case  6: fir4< 6>(GH_, B0_, B1_, B2_, B3_, CC, ACC); break; \
    case  5: fir4< 5>(GH_, B0_, B1_, B2_, B3_, CC, ACC); break; \
    case  4: fir4< 4>(GH_, B0_, B1_, B2_, B3_, CC, ACC); break; \
    case  3: fir4< 3>(GH_, B0_, B1_, B2_, B3_, CC, ACC); break; \
    case  2: fir4< 2>(GH_, B0_, B1_, B2_, B3_, CC, ACC); break; \
    default: fir4< 1>(GH_, B0_, B1_, B2_, B3_, CC, ACC); break; \
  }

__global__ __launch_bounds__(THREADS, 2) void hpbc_kernel(
    const float2* __restrict__ er, const float2* __restrict__ ei,
    const float2* __restrict__ fr, const float2* __restrict__ fi,
    const float*  __restrict__ task, const float4* __restrict__ cw,
    unsigned short* __restrict__ out, int nout, int lpad, int ntiles)
{
  __shared__ float4 sE4[4][WINQ];      // E: u -> [u&3][u>>2]
  __shared__ float4 sF[WIN];
  __shared__ float4 ghA[4 * GHQ];      // mod-4 split, double-buffered
  __shared__ float4 ghB[4 * GHQ];

  const int bx   = blockIdx.x;
  const int b    = bx / ntiles;
  const int tile = bx - b * ntiles;
  const int tid  = threadIdx.x;
  const int i0   = lpad + tile * TILE;
  const int elo  = i0 - 2 * NM;

  const float2* erb = er + (size_t)b * NSEQ;
  const float2* eib = ei + (size_t)b * NSEQ;
  const float2* frb = fr + (size_t)b * NSEQ;
  const float2* fib = fi + (size_t)b * NSEQ;

  for (int u = tid; u < WIN; u += THREADS) {
    int g = (elo + u) & (NSEQ - 1);                  // exact jnp.roll wrap
    float2 a = erb[g], c = eib[g];
    sE4[u & 3][u >> 2] = make_float4(a.x, c.x, a.y, c.y);
    float2 d = frb[g], e = fib[g];
    sF[u] = make_float4(d.x, e.x, d.y, e.y);
  }

  const float dbm = task[b * 4 + 0];
  const float fsr = task[b * 4 + 2];
  const int   x   = (int)(fsr / 2.0e9f);
  const int ind = (x == 40) ? 1 : (x == 80) ? 2 : (x == 160) ? 3 : 0;
  const float4* __restrict__ crow = cw + ind * KTAPS;
  const float4* __restrict__ cswp = cw + 4 * KTAPS + ind * KTAPS;
  const float P  = powf(10.0f, dbm * 0.1f) * 0.5f;
  const float pf = P * sqrtf(P);

  __syncthreads();

  // GH hoists: entries bi = tid + 256k; all share one E-plane.
  const int pE = (tid + NM) & 3, iE = (tid + NM) >> 2;
  float4 eH[5], fH[5];
#pragma unroll
  for (int k = 0; k < 4; ++k) { eH[k] = sE4[pE][iE + 64 * k]; fH[k] = sF[tid + NM + 256 * k]; }
  const bool has5 = tid < GHW - 4 * THREADS;   // tid < 51
  if (has5) { eH[4] = sE4[pE][iE + 256]; fH[4] = sF[tid + NM + 1024]; }

  const int wbase = (tid & 3) * GHQ + (tid >> 2);   // write slot for bi=tid

  auto write_gh = [&](float4* wGH, int Mn) {
    const int s  = NM - Mn;
    const int pS = (tid + s) & 3, iS = (tid + s) >> 2;
#pragma unroll
    for (int k = 0; k < 4; ++k) {
      const float4 fm = sF[tid + s + 256 * k];
      const float4 em = sE4[pS][iS + 64 * k];
      wGH[wbase + 64 * k] = gh_entry(eH[k], fH[k], fm, em);
    }
    if (has5) {
      const float4 fm = sF[tid + s + 1024];
      const float4 em = sE4[pS][iS + 256];
      wGH[wbase + 256] = gh_entry(eH[4], fH[4], fm, em);
    }
  };

  v2f O0[4], O1[4];
#pragma unroll
  for (int r = 0; r < 4; ++r) { O0[r] = (v2f){0, 0}; O1[r] = (v2f){0, 0}; }
  int kbaseP = 199, kbaseN = 199;

  // Sliding e-windows: W_p[r] = E[u=4tid+r+50-M], W_m[r] = E[u=4tid+r+50+M].
  float4 W_p[4], W_m[4];
#pragma unroll
  for (int r = 0; r < 4; ++r) {
    const int u = 4 * tid + r + 2 * NM;
    W_p[r] = sE4[u & 3][u >> 2];
    W_m[r] = W_p[r];
  }

  auto iter = [&](const float4* rGH, float4* wGH, int M) {
    const int nmax = (M == 0) ? NM : (NM / M);
    const int T    = 2 * nmax + 1;

    // ---- FIR(+M) ----
    {
      const int X = 28 + nmax;
      const int B0 = ((X    ) & 3) * GHQ + tid + ((X    ) >> 2);
      const int B1 = ((X - 1) & 3) * GHQ + tid + ((X - 1) >> 2);
      const int B2 = ((X - 2) & 3) * GHQ + tid + ((X - 2) >> 2);
      const int B3 = ((X - 3) & 3) * GHQ + tid + ((X - 3) >> 2);
      v2f acc[16];
#pragma unroll
      for (int j = 0; j < 16; ++j) acc[j] = (v2f){0, 0};
      FIR_SWITCH(nmax, rGH, B0, B1, B2, B3, crow + kbaseP, acc);
      kbaseP += T;
#pragma unroll
      for (int r = 0; r < 4; ++r) {
        const float sr = acc[4*r].x - acc[4*r+1].y + acc[4*r+2].x - acc[4*r+3].y;
        const float si = acc[4*r].y + acc[4*r+1].x + acc[4*r+2].y + acc[4*r+3].x;
        const float4 e = W_p[r];
        O0[r] = pkfma(sr, (v2f){e.x, e.y}, pkfma(si, (v2f){-e.y, e.x}, O0[r]));
        O1[r] = pkfma(sr, (v2f){e.z, e.w}, pkfma(si, (v2f){-e.w, e.z}, O1[r]));
      }
    }

    // ---- FIR(-M): shared buffer, base +M, swapped-c, conj reduction ----
    if (M > 0) {
      kbaseN -= T;
      const int X = 28 + nmax + M;
      const int B0 = ((X    ) & 3) * GHQ + tid + ((X    ) >> 2);
      const int B1 = ((X - 1) & 3) * GHQ + tid + ((X - 1) >> 2);
      const int B2 = ((X - 2) & 3) * GHQ + tid + ((X - 2) >> 2);
      const int B3 = ((X - 3) & 3) * GHQ + tid + ((X - 3) >> 2);
      v2f acc[16];
#pragma unroll
      for (int j = 0; j < 16; ++j) acc[j] = (v2f){0, 0};
      FIR_SWITCH(nmax, rGH, B0, B1, B2, B3, cswp + kbaseN, acc);
#pragma unroll
      for (int r = 0; r < 4; ++r) {
        const float sr = acc[4*r].x + acc[4*r+1].y + acc[4*r+2].x + acc[4*r+3].y;
        const float si = acc[4*r+1].x - acc[4*r].y + acc[4*r+3].x - acc[4*r+2].y;
        const float4 e = W_m[r];
        O0[r] = pkfma(sr, (v2f){e.x, e.y}, pkfma(si, (v2f){-e.y, e.x}, O0[r]));
        O1[r] = pkfma(sr, (v2f){e.z, e.w}, pkfma(si, (v2f){-e.w, e.z}, O1[r]));
      }
    }

    if (M < NM) write_gh(wGH, M + 1);

    // Slide windows to M+1 (2 new LDS reads).
    {
      const int up = 4 * tid + 2 * NM - (M + 1);       // >= 4tid+24
      W_p[3] = W_p[2]; W_p[2] = W_p[1]; W_p[1] = W_p[0];
      W_p[0] = sE4[up & 3][up >> 2];
      const int um = 4 * tid + 3 + 2 * NM + (M + 1);   // <= 4tid+79
      W_m[0] = W_m[1]; W_m[1] = W_m[2]; W_m[2] = W_m[3];
      W_m[3] = sE4[um & 3][um >> 2];
    }

    __syncthreads();
  };

  // Prologue: GH(order 0) into buffer A.
  write_gh(ghA, 0);
  __syncthreads();

  for (int M = 0; M <= NM; M += 2) {
    iter(ghA, ghB, M);
    if (M + 1 <= NM)
      iter(ghB, ghA, M + 1);
  }

  // ---- Epilogue: (IMAG, REAL) element order ----
  const int end = lpad + nout;
  const size_t chunk1 = (size_t)BATCH * nout * 4;
#pragma unroll
  for (int r = 0; r < 4; ++r) {
    const int ii = 4 * tid + r;
    const int i  = i0 + ii;
    if (i < end) {
      const int u = ii + 2 * NM;
      const float4 ev = sE4[u & 3][u >> 2];
      const float4 fv = sF[u];
      const size_t o = ((size_t)b * nout + (size_t)(i - lpad)) * 4;
      ushort4 w0, w1;
      w0.x = f2bf(ev.y); w0.y = f2bf(ev.x); w0.z = f2bf(ev.w); w0.w = f2bf(ev.z);
      w1.x = f2bf(fv.y + pf * O0[r].y); w1.y = f2bf(fv.x + pf * O0[r].x);
      w1.z = f2bf(fv.w + pf * O1[r].y); w1.w = f2bf(fv.z + pf * O1[r].x);
      *reinterpret_cast<ushort4*>(out + o) = w0;
      *reinterpret_cast<ushort4*>(out + chunk1 + o) = w1;
    }
  }
}

} // namespace

extern "C" void kernel_launch(void* const* d_in, const int* in_sizes, int n_in,
                              void* d_out, int out_size, void* d_ws, size_t ws_size,
                              hipStream_t stream) {
  const float* E_real  = (const float*)d_in[0];
  const float* E_imag  = (const float*)d_in[1];
  const float* F_real  = (const float*)d_in[2];
  const float* F_imag  = (const float*)d_in[3];
  const float* C1_real = (const float*)d_in[4];
  const float* C1_imag = (const float*)d_in[5];
  const float* C2_real = (const float*)d_in[6];
  const float* C2_imag = (const float*)d_in[7];
  const float* task    = (const float*)d_in[8];

  int nout = out_size / 32;
  if (nout < 1 || nout > NSEQ) nout = NSEQ - 100;
  const int lpad   = (NSEQ - nout) / 2;             // 50
  const int ntiles = (nout + TILE - 1) / TILE;      // 64

  unsigned short* outp = (unsigned short*)d_out;
  float4* cw = (float4*)d_ws;                       // 2 tables: 57,472 B

  hipLaunchKernelGGL(prep_c_kernel, dim3((4 * KTAPS + 255) / 256), dim3(256), 0, stream,
                     C1_real, C1_imag, C2_real, C2_imag, cw);

  hipLaunchKernelGGL(hpbc_kernel, dim3(BATCH * ntiles), dim3(THREADS), 0, stream,
                     (const float2*)E_real, (const float2*)E_imag,
                     (const float2*)F_real, (const float2*)F_imag,
                     task, cw, outp, nout, lpad, ntiles);
}